// Round 1
// baseline (933.849 us; speedup 1.0000x reference)
//
#include <hip/hip_runtime.h>

#define B_ 2
#define H_ 16
#define S_ 2048
#define D_ 64
#define QB 32
#define KT 64
#define NT (S_ / KT)
#define NTHREADS 512

typedef _Float16 f16;
typedef _Float16 f16x8 __attribute__((ext_vector_type(8)));
typedef _Float16 f16x4 __attribute__((ext_vector_type(4)));
typedef _Float16 f16x2 __attribute__((ext_vector_type(2)));
typedef float f32x4 __attribute__((ext_vector_type(4)));

#define MFMA16(a, b, c) __builtin_amdgcn_mfma_f32_16x16x32_f16(a, b, c, 0, 0, 0)

__global__ __launch_bounds__(NTHREADS)
void attn_kernel(const float* __restrict__ q, const float* __restrict__ k,
                 const float* __restrict__ v, const int* __restrict__ mask,
                 float* __restrict__ out)
{
    // Double-buffered tiles, ~51 KB total -> still 3 blocks/CU (thread cap = 4)
    __shared__ f16 Qsh[QB][D_ + 8];        // 32x72, [q][d]
    __shared__ f16 Ksh[2][KT][D_ + 8];     // 2x64x72, [key][d] (row-major)
    __shared__ f16 Vt [2][D_][KT + 8];     // 2x64x72, [d][key] (TRANSPOSED: b128 B-frag reads)
    __shared__ f16 Psh[2][QB][KT + 8];     // 2x32x72
    __shared__ float rowred[QB];
    __shared__ float rlsh[QB];

    const int tid  = threadIdx.x;
    const int wave = tid >> 6;
    const int lane = tid & 63;
    const int quad = lane >> 4;
    const int l16  = lane & 15;
    const int qi   = wave & 1;   // q 16-row half
    const int ni   = wave >> 1;  // score col / O d-col 16-block

    const int qb = blockIdx.x;
    const int h  = blockIdx.y;
    const int b  = blockIdx.z;
    const int bh = b * H_ + h;

    const float* Qg = q + ((size_t)bh * S_ + (size_t)qb * QB) * D_;
    const float* Kg = k + (size_t)bh * S_ * D_;
    const float* Vg = v + (size_t)bh * S_ * D_;
    const int*   Mg = mask + ((size_t)b * S_ + (size_t)qb * QB) * S_;
    float* res_out  = out + ((size_t)bh * S_ + (size_t)qb * QB) * D_;
    float* attn_out = out + (size_t)B_ * H_ * S_ * D_
                          + ((size_t)bh * S_ + (size_t)qb * QB) * S_;

    if (tid < QB) rowred[tid] = 0.f;

    // ---- stage Q (scale 1/8 folded in; exact in fp16: power of 2) ----
    {
        const int row = tid >> 4;
        const int c4  = (tid & 15) * 4;
        const float4 qv = *(const float4*)(Qg + row * D_ + c4);
        f16x4 o;
        o[0] = (f16)(qv.x * 0.125f); o[1] = (f16)(qv.y * 0.125f);
        o[2] = (f16)(qv.z * 0.125f); o[3] = (f16)(qv.w * 0.125f);
        *(f16x4*)&Qsh[row][c4] = o;
    }

    // staging coordinates
    const int skk = tid >> 3;        // K: row (0..63)
    const int sd0 = (tid & 7) * 8;   // K: d-col
    const int vkp = tid & 31;        // V: key-PAIR index (rows 2*vkp, 2*vkp+1) -> bank-spread writes
    const int vd0 = (tid >> 5) * 4;  // V: d-quad

    const int qrow0   = qi * 16 + quad * 4;
    const int colbase = ni * 16 + l16;
    const int* mp0 = Mg + (size_t)qrow0 * S_ + colbase;

    // ---- sweep-1 prologue: stage K tile 0 into buf 0, prefetch mask tile 0 ----
    {
        const float* src = Kg + (size_t)skk * D_ + sd0;
        const float4 x0 = *(const float4*)(src);
        const float4 x1 = *(const float4*)(src + 4);
        f16x8 o;
        o[0] = (f16)x0.x; o[1] = (f16)x0.y; o[2] = (f16)x0.z; o[3] = (f16)x0.w;
        o[4] = (f16)x1.x; o[5] = (f16)x1.y; o[6] = (f16)x1.z; o[7] = (f16)x1.w;
        *(f16x8*)&Ksh[0][skk][sd0] = o;
    }
    int mnext[4];
#pragma unroll
    for (int r = 0; r < 4; ++r) mnext[r] = mp0[(size_t)r * S_];
    __syncthreads();

    // hoisted A-fragments: A[m=l16][k=quad*8+j], K=64 -> two frags
    const f16x8 a0 = *(const f16x8*)&Qsh[qi * 16 + l16][quad * 8];
    const f16x8 a1 = *(const f16x8*)&Qsh[qi * 16 + l16][32 + quad * 8];

    // ================= sweep 1: row sums of exp (1 barrier / tile) =================
    float psum[4] = {0.f, 0.f, 0.f, 0.f};
    for (int kt = 0; kt < NT; ++kt) {
        const int cur = kt & 1;
        const int ktn = (kt + 1 < NT) ? kt + 1 : kt;   // clamped: last iter redundant
        // issue next-tile K loads + next mask NOW; consumed after compute (latency hidden)
        const float* srck = Kg + ((size_t)(ktn * KT + skk)) * D_ + sd0;
        const float4 x0 = *(const float4*)(srck);
        const float4 x1 = *(const float4*)(srck + 4);
        int mcur[4];
#pragma unroll
        for (int r = 0; r < 4; ++r) mcur[r] = mnext[r];
        const int* mpn = mp0 + ktn * KT;
#pragma unroll
        for (int r = 0; r < 4; ++r) mnext[r] = mpn[(size_t)r * S_];

        // scores from current buffer
        const f16x8 b0 = *(const f16x8*)&Ksh[cur][ni * 16 + l16][quad * 8];
        const f16x8 b1 = *(const f16x8*)&Ksh[cur][ni * 16 + l16][32 + quad * 8];
        f32x4 c = {0.f, 0.f, 0.f, 0.f};
        c = MFMA16(a0, b0, c);
        c = MFMA16(a1, b1, c);
#pragma unroll
        for (int r = 0; r < 4; ++r)
            psum[r] += (mcur[r] == 1) ? 0.f : __expf(c[r]);

        // commit prefetched K into the other buffer (readers of it finished before
        // the PREVIOUS barrier; visible to everyone after the barrier below)
        {
            f16x8 o;
            o[0] = (f16)x0.x; o[1] = (f16)x0.y; o[2] = (f16)x0.z; o[3] = (f16)x0.w;
            o[4] = (f16)x1.x; o[5] = (f16)x1.y; o[6] = (f16)x1.z; o[7] = (f16)x1.w;
            *(f16x8*)&Ksh[cur ^ 1][skk][sd0] = o;
        }
        __syncthreads();
    }

    // reduce psum across the 16 column-lanes of each quad
#pragma unroll
    for (int r = 0; r < 4; ++r) {
        psum[r] += __shfl_xor(psum[r], 1);
        psum[r] += __shfl_xor(psum[r], 2);
        psum[r] += __shfl_xor(psum[r], 4);
        psum[r] += __shfl_xor(psum[r], 8);
    }
    if (l16 == 0) {
#pragma unroll
        for (int r = 0; r < 4; ++r) atomicAdd(&rowred[qrow0 + r], psum[r]);
    }
    __syncthreads();
    if (tid < QB) rlsh[tid] = 1.0f / rowred[tid];
    __syncthreads();
    float rlq[4];
#pragma unroll
    for (int r = 0; r < 4; ++r) rlq[r] = rlsh[qrow0 + r];

    // ---- sweep-2 prologue: stage K0 + V0 into buf 0, re-prefetch mask tile 0 ----
    {
        const float* srck = Kg + (size_t)skk * D_ + sd0;
        const float4 x0 = *(const float4*)(srck);
        const float4 x1 = *(const float4*)(srck + 4);
        f16x8 o;
        o[0] = (f16)x0.x; o[1] = (f16)x0.y; o[2] = (f16)x0.z; o[3] = (f16)x0.w;
        o[4] = (f16)x1.x; o[5] = (f16)x1.y; o[6] = (f16)x1.z; o[7] = (f16)x1.w;
        *(f16x8*)&Ksh[0][skk][sd0] = o;

        const float* srcv = Vg + (size_t)(2 * vkp) * D_ + vd0;
        const float4 y0 = *(const float4*)(srcv);        // row 2*vkp
        const float4 y1 = *(const float4*)(srcv + D_);   // row 2*vkp+1
#pragma unroll
        for (int j = 0; j < 4; ++j) {
            f16x2 pr;
            pr[0] = (f16)((&y0.x)[j]);
            pr[1] = (f16)((&y1.x)[j]);
            *(f16x2*)&Vt[0][vd0 + j][2 * vkp] = pr;      // transposed store
        }
#pragma unroll
        for (int r = 0; r < 4; ++r) mnext[r] = mp0[(size_t)r * S_];
    }
    __syncthreads();

    // ================= sweep 2: write attn, accumulate O (2 barriers / tile) =================
    f32x4 oacc = {0.f, 0.f, 0.f, 0.f};
    float* ap0 = attn_out + (size_t)qrow0 * S_ + colbase;
    const int dcol = colbase;

    for (int kt = 0; kt < NT; ++kt) {
        const int cur = kt & 1;
        const int nxt = cur ^ 1;
        const int ktn = (kt + 1 < NT) ? kt + 1 : kt;

        // ---- issue next-tile K,V,mask loads (kept in regs until after PV) ----
        const float* srck = Kg + ((size_t)(ktn * KT + skk)) * D_ + sd0;
        const float4 x0 = *(const float4*)(srck);
        const float4 x1 = *(const float4*)(srck + 4);
        const float* srcv = Vg + ((size_t)(ktn * KT + 2 * vkp)) * D_ + vd0;
        const float4 y0 = *(const float4*)(srcv);
        const float4 y1 = *(const float4*)(srcv + D_);
        int mcur[4];
#pragma unroll
        for (int r = 0; r < 4; ++r) mcur[r] = mnext[r];
        const int* mpn = mp0 + ktn * KT;
#pragma unroll
        for (int r = 0; r < 4; ++r) mnext[r] = mpn[(size_t)r * S_];

        // ---- scores (recompute) from Ksh[cur] ----
        const f16x8 b0 = *(const f16x8*)&Ksh[cur][ni * 16 + l16][quad * 8];
        const f16x8 b1 = *(const f16x8*)&Ksh[cur][ni * 16 + l16][32 + quad * 8];
        f32x4 c = {0.f, 0.f, 0.f, 0.f};
        c = MFMA16(a0, b0, c);
        c = MFMA16(a1, b1, c);
        float* ap = ap0 + kt * KT;
#pragma unroll
        for (int r = 0; r < 4; ++r) {
            const float e = (mcur[r] == 1) ? 0.f : __expf(c[r]);
            const float p = e * rlq[r];
            ap[(size_t)r * S_] = p;                      // attn output
            Psh[cur][qrow0 + r][colbase] = (f16)p;       // C-layout -> A-layout via LDS
        }
        __syncthreads();   // P[cur] visible; everyone done with Ksh[cur] reads

        // ---- PV: all-b128 fragment reads (Vt transposed) ----
        const f16x8 pa0 = *(const f16x8*)&Psh[cur][qi * 16 + l16][quad * 8];
        const f16x8 pa1 = *(const f16x8*)&Psh[cur][qi * 16 + l16][32 + quad * 8];
        const f16x8 vb0 = *(const f16x8*)&Vt[cur][dcol][quad * 8];
        const f16x8 vb1 = *(const f16x8*)&Vt[cur][dcol][32 + quad * 8];
        oacc = MFMA16(pa0, vb0, oacc);
        oacc = MFMA16(pa1, vb1, oacc);

        // ---- commit prefetched K,V into the other buffer ----
        // (last reads of buf[nxt] were in iter kt-1, strictly before this point's
        //  preceding barrier; write is race-free, published by the barrier below)
        {
            f16x8 o;
            o[0] = (f16)x0.x; o[1] = (f16)x0.y; o[2] = (f16)x0.z; o[3] = (f16)x0.w;
            o[4] = (f16)x1.x; o[5] = (f16)x1.y; o[6] = (f16)x1.z; o[7] = (f16)x1.w;
            *(f16x8*)&Ksh[nxt][skk][sd0] = o;
        }
#pragma unroll
        for (int j = 0; j < 4; ++j) {
            f16x2 pr;
            pr[0] = (f16)((&y0.x)[j]);
            pr[1] = (f16)((&y1.x)[j]);
            *(f16x2*)&Vt[nxt][vd0 + j][2 * vkp] = pr;
        }
        __syncthreads();
    }

    // res: rows qrow0+r, col = ni*16+l16 (1/l already folded into P)
#pragma unroll
    for (int r = 0; r < 4; ++r)
        res_out[(size_t)(qrow0 + r) * D_ + ni * 16 + l16] = oacc[r];
}

extern "C" void kernel_launch(void* const* d_in, const int* in_sizes, int n_in,
                              void* d_out, int out_size, void* d_ws, size_t ws_size,
                              hipStream_t stream) {
    (void)in_sizes; (void)n_in; (void)out_size; (void)d_ws; (void)ws_size;
    const float* q   = (const float*)d_in[0];
    const float* k   = (const float*)d_in[1];
    const float* v   = (const float*)d_in[2];
    const int*  mask = (const int*)d_in[3];
    float* out = (float*)d_out;
    dim3 grid(S_ / QB, H_, B_);   // qblock fastest -> K/V L2 reuse; mask from L3
    attn_kernel<<<grid, dim3(NTHREADS), 0, stream>>>(q, k, v, mask, out);
}